// Round 1
// baseline (261.361 us; speedup 1.0000x reference)
//
#include <hip/hip_runtime.h>

#define B_ 2
#define C_ 512
#define H_ 50
#define W_ 75
#define N_ 2000
#define SS (1.0f/16.0f)

// (B,C,H,W) -> (B,H,W,C) tiled transpose, 32x32 tiles, 32x8 threads
__global__ __launch_bounds__(256) void transpose_k(const float* __restrict__ in,
                                                   float* __restrict__ out) {
    __shared__ float tile[32][33];
    const int b   = blockIdx.z;
    const int hw0 = blockIdx.x * 32;
    const int c0  = blockIdx.y * 32;
    const int tx  = threadIdx.x;   // 0..31
    const int ty  = threadIdx.y;   // 0..7
    #pragma unroll
    for (int r = 0; r < 32; r += 8) {
        int c  = c0 + ty + r;
        int hw = hw0 + tx;
        if (c < C_ && hw < H_ * W_)
            tile[ty + r][tx] = in[(b * C_ + c) * (H_ * W_) + hw];
    }
    __syncthreads();
    #pragma unroll
    for (int r = 0; r < 32; r += 8) {
        int hw = hw0 + ty + r;
        int c  = c0 + tx;
        if (hw < H_ * W_ && c < C_)
            out[(b * (H_ * W_) + hw) * C_ + c] = tile[tx][ty + r];
    }
}

// One block per roi. 256 threads: lane = channel-within-chunk (64),
// wave = sample-group (4 waves x 16 samples = 64 sample points).
__global__ __launch_bounds__(256) void roi_avg_k(
    const float* __restrict__ ft, const float* __restrict__ rois,
    float* __restrict__ out, int sB, int sH, int sW, int sC)
{
    __shared__ float  sval[64 * 65];   // [sample][channel], stride 65: conflict-free
    __shared__ float4 swt[64];         // bilinear weights per sample
    __shared__ int    soff[64];        // base element offset per sample

    const int n   = blockIdx.x;
    const int tid = threadIdx.x;

    if (tid < 64) {
        const int s = tid;
        const int j = s >> 3;          // y sample index 0..7
        const int i = s & 7;           // x sample index 0..7
        const float bf = rois[n * 5 + 0];
        const float x1 = rois[n * 5 + 1] * SS;
        const float y1 = rois[n * 5 + 2] * SS;
        const float x2 = rois[n * 5 + 3] * SS;
        const float y2 = rois[n * 5 + 4] * SS;
        const int b = (int)bf;
        const float roi_w = fmaxf(x2 - x1 + 1.0f, 0.0f);
        const float roi_h = fmaxf(y2 - y1 + 1.0f, 0.0f);
        const float bin_h = roi_h / 7.0f;
        const float bin_w = roi_w / 7.0f;
        const float h = y1 + (float)j * bin_h;
        const float w = x1 + (float)i * bin_w;
        const bool valid = (h >= 0.0f) && (h < (float)H_) &&
                           (w >= 0.0f) && (w < (float)W_);
        int hs = (int)floorf(h); hs = hs < 0 ? 0 : (hs > H_ - 2 ? H_ - 2 : hs);
        int ws = (int)floorf(w); ws = ws < 0 ? 0 : (ws > W_ - 2 ? W_ - 2 : ws);
        const float hr = h - (float)hs;
        const float wr = w - (float)ws;
        const float vz = valid ? 1.0f : 0.0f;   // zero weights => val = 0 (matches where())
        float4 wt;
        wt.x = (1.0f - hr) * (1.0f - wr) * vz;
        wt.y = (1.0f - hr) * wr * vz;
        wt.z = hr * (1.0f - wr) * vz;
        wt.w = hr * wr * vz;
        swt[s]  = wt;
        soff[s] = b * sB + hs * sH + ws * sW;
    }
    __syncthreads();

    const int lane = tid & 63;
    const int wv   = tid >> 6;
    const int dW   = sW;
    const int dH   = sH;
    const int dHW  = sH + sW;

    for (int chunk = 0; chunk < C_ / 64; ++chunk) {
        const int cbase = (chunk * 64 + lane) * sC;
        #pragma unroll 4
        for (int k = 0; k < 16; ++k) {
            const int s = wv * 16 + k;
            const float4 wt = swt[s];
            const int off = soff[s] + cbase;
            const float v = ft[off]       * wt.x + ft[off + dW]  * wt.y +
                            ft[off + dH]  * wt.z + ft[off + dHW] * wt.w;
            sval[s * 65 + lane] = v;       // wave writes one contiguous row: no conflicts
        }
        __syncthreads();
        const int out_base = n * (C_ * 49) + chunk * (64 * 49);
        #pragma unroll
        for (int r = 0; r < 13; ++r) {
            const int o = r * 256 + tid;
            if (o < 64 * 49) {
                const int c  = o / 49;
                const int ji = o - c * 49;
                const int jj = ji / 7;
                const int s  = ji + jj;    // j*8+i == (j*7+i) + j
                const float v = 0.25f * (sval[s * 65 + c]       + sval[(s + 1) * 65 + c] +
                                         sval[(s + 8) * 65 + c] + sval[(s + 9) * 65 + c]);
                out[out_base + o] = v;     // contiguous per (roi, chunk): coalesced
            }
        }
        __syncthreads();
    }
}

extern "C" void kernel_launch(void* const* d_in, const int* in_sizes, int n_in,
                              void* d_out, int out_size, void* d_ws, size_t ws_size,
                              hipStream_t stream) {
    const float* features = (const float*)d_in[0];
    const float* rois     = (const float*)d_in[1];
    float* out            = (float*)d_out;

    const size_t need = (size_t)B_ * C_ * H_ * W_ * sizeof(float);
    if (ws_size >= need) {
        float* ftT = (float*)d_ws;
        dim3 g((H_ * W_ + 31) / 32, (C_ + 31) / 32, B_);
        dim3 b(32, 8, 1);
        transpose_k<<<g, b, 0, stream>>>(features, ftT);
        // (B,H,W,C) strides in elements
        roi_avg_k<<<N_, 256, 0, stream>>>(ftT, rois, out,
                                          H_ * W_ * C_, W_ * C_, C_, 1);
    } else {
        // fallback: native (B,C,H,W) strides
        roi_avg_k<<<N_, 256, 0, stream>>>(features, rois, out,
                                          C_ * H_ * W_, W_, 1, H_ * W_);
    }
}